// Round 6
// baseline (46.853 us; speedup 1.0000x reference)
//
#include <hip/hip_runtime.h>

// QRNN fused kernel for MI355X.
// B=64, S=2048, VOCAB=128, HIDDEN=256, gates=768, emb=124, num=7.
//
//  - precompute_kernel (one grid, three roles):
//      blocks 0..63   : GEMM G[768][128e] = Wc[:,:124] @ emb^T (emb^T in LDS, pad 129),
//                       b_num folded via bias. Writes exp2-domain tables
//                       G2[e][j] = (z', f') (f32x2, 2KB rows) and Go[e][j] = o'.
//      block  64      : Wg2/Wgo numeric weights (Wc[:,124:]@W_num, scaled) + 4 zero
//                       pad records at Xp[B*S..B*S+3] (branch-free scan prefetch).
//      blocks 65..192 : packed records Xp[b*S+t] = {eo=e<<11, x0..x6} (32B).
//  - scan_kernel: affine recurrence h = f*h + (1-f)*z, chunked scan (32 x 64 steps).
//      256 thr/block, 1 channel/thread (round-4 shape: TLP matters). ALL loads are
//      VMEM (in-order vmcnt -> fine-grained waits; SMEM lgkmcnt retires out-of-order
//      and forces coarse drains). Explicit static rings (#unroll 4, &3 indices):
//      records depth-3-ahead, G2 rows depth-2-ahead -> software pipeline covers the
//      ~220cy L2 gather that bounded rounds 4/5. Shared-rcp activation: 3 trans/step.
//  - combine_kernel: fold 32 chunk affines, apply o (last step), dot W_out.

typedef float f32x2 __attribute__((ext_vector_type(2)));
typedef float f32x4 __attribute__((ext_vector_type(4)));

#define NB 64
#define NS 2048
#define NH 256
#define CHUNKS 32
#define STEPS (NS / CHUNKS)   // 64
#define LOG2E 1.4426950408889634f
#define PAD 129

__global__ __launch_bounds__(256) void precompute_kernel(
    const float* __restrict__ X,     // [B][S][8]
    const float* __restrict__ emb,   // [128][124]
    const float* __restrict__ Wn,    // [4][7]
    const float* __restrict__ bn,    // [4]
    const float* __restrict__ Wc,    // [768][128]
    const float* __restrict__ bc,    // [768]
    f32x2* __restrict__ G2,          // out [128e][256j]  (z', f') exp2-domain
    float* __restrict__ Go,          // out [128e][256j]  o'
    f32x2* __restrict__ Wg2,         // out [7][256]
    float* __restrict__ Wgo,         // out [7][256]
    float* __restrict__ Xp)          // out [B*S+4][8] packed records
{
    __shared__ float M[124 * PAD];   // emb^T staged: M[k*PAD + e] = emb[e][k]
    const int tid = threadIdx.x;
    const int blk = blockIdx.x;

    if (blk < 64) {
        {
            const int e = tid >> 1, half = tid & 1;
            const f32x4* er4 = (const f32x4*)(emb + (size_t)e * 124);
            #pragma unroll
            for (int i = 0; i < 16; ++i) {
                const int idx = half * 16 + i;
                if (idx < 31) {
                    const f32x4 v = er4[idx];
                    const int k0 = idx * 4;
                    M[(k0 + 0) * PAD + e] = v.x;
                    M[(k0 + 1) * PAD + e] = v.y;
                    M[(k0 + 2) * PAD + e] = v.z;
                    M[(k0 + 3) * PAD + e] = v.w;
                }
            }
        }
        __syncthreads();

        const int e = tid & 127;
        const int s = tid >> 7;
        const int j0 = blk * 4 + s * 2;   // channels j0, j0+1

        float bnv[4];
        #pragma unroll
        for (int m = 0; m < 4; ++m) bnv[m] = bn[m];

        float acc[2][3] = {{0.f,0.f,0.f},{0.f,0.f,0.f}};
        const f32x4* wz4[2]; const f32x4* wf4[2]; const f32x4* wo4[2];
        #pragma unroll
        for (int i = 0; i < 2; ++i) {
            wz4[i] = (const f32x4*)(Wc + (size_t)(j0 + i) * 128);
            wf4[i] = (const f32x4*)(Wc + (size_t)(j0 + i + 256) * 128);
            wo4[i] = (const f32x4*)(Wc + (size_t)(j0 + i + 512) * 128);
        }

        for (int kb = 0; kb < 31; ++kb) {
            f32x4 w[2][3];
            #pragma unroll
            for (int i = 0; i < 2; ++i) {
                w[i][0] = wz4[i][kb];
                w[i][1] = wf4[i][kb];
                w[i][2] = wo4[i][kb];
            }
            #pragma unroll
            for (int u = 0; u < 4; ++u) {
                const float mv = M[(kb * 4 + u) * PAD + e];
                #pragma unroll
                for (int i = 0; i < 2; ++i) {
                    acc[i][0] = fmaf(w[i][0][u], mv, acc[i][0]);
                    acc[i][1] = fmaf(w[i][1][u], mv, acc[i][1]);
                    acc[i][2] = fmaf(w[i][2][u], mv, acc[i][2]);
                }
            }
        }

        #pragma unroll
        for (int i = 0; i < 2; ++i) {
            const int j = j0 + i;
            float az = acc[i][0] + bc[j];
            float af = acc[i][1] + bc[j + 256];
            float ao = acc[i][2] + bc[j + 512];
            const f32x4 tz = wz4[i][31];
            const f32x4 tf = wf4[i][31];
            const f32x4 to = wo4[i][31];
            #pragma unroll
            for (int m = 0; m < 4; ++m) {
                az = fmaf(tz[m], bnv[m], az);
                af = fmaf(tf[m], bnv[m], af);
                ao = fmaf(to[m], bnv[m], ao);
            }
            G2[(size_t)e * NH + j] = (f32x2){az * (-2.0f * LOG2E), af * (-LOG2E)};
            Go[(size_t)e * NH + j] = ao * (-LOG2E);
        }
    } else if (blk == 64) {
        if (tid < 256) {
            const int j = tid;
            #pragma unroll
            for (int n = 0; n < 7; ++n) {
                float sz = 0.0f, sf = 0.0f, so = 0.0f;
                #pragma unroll
                for (int m = 0; m < 4; ++m) {
                    const float wnm = Wn[m * 7 + n];
                    sz = fmaf(Wc[(size_t)j * 128 + 124 + m], wnm, sz);
                    sf = fmaf(Wc[(size_t)(j + 256) * 128 + 124 + m], wnm, sf);
                    so = fmaf(Wc[(size_t)(j + 512) * 128 + 124 + m], wnm, so);
                }
                Wg2[n * NH + j] = (f32x2){sz * (-2.0f * LOG2E), sf * (-LOG2E)};
                Wgo[n * NH + j] = so * (-LOG2E);
            }
        }
        if (tid < 32) {
            Xp[(size_t)NB * NS * 8 + tid] = 0.0f;   // 4 zero pad records (eo=0)
        }
    } else {
        // packed record extraction: 128 blocks x 1024 records
        const f32x4* X4 = (const f32x4*)X;
        f32x4* Xp4 = (f32x4*)Xp;
        const int base = (blk - 65) * 1024 + tid;
        #pragma unroll
        for (int u = 0; u < 4; ++u) {
            const int idx = base + u * 256;
            f32x4 xa = X4[(size_t)idx * 2];
            const f32x4 xb = X4[(size_t)idx * 2 + 1];
            xa.x = __int_as_float(((int)xa.x) << 11);   // byte offset of G2 row (2KB)
            Xp4[(size_t)idx * 2]     = xa;
            Xp4[(size_t)idx * 2 + 1] = xb;
        }
    }
}

__global__ __launch_bounds__(256) void scan_kernel(
    const float* __restrict__ Xp,    // [B*S+4][8] packed records
    const f32x2* __restrict__ G2,    // [128][256]
    const float* __restrict__ Go,    // [128][256]
    const f32x2* __restrict__ Wg2,   // [7][256]
    const float* __restrict__ Wgo,   // [7][256]
    float* __restrict__ AB,          // [CHUNKS][B][2][256]
    float* __restrict__ Olast)       // [B][256]
{
    const int b = blockIdx.x;
    const int c = blockIdx.y;
    const int j = threadIdx.x;

    const f32x4* __restrict__ xp =
        (const f32x4*)(Xp + ((size_t)b * NS + (size_t)c * STEPS) * 8);
    const char* __restrict__ g2b = (const char*)G2;
    const int j8 = j * 8;

    f32x2 w2[7];
    #pragma unroll
    for (int n = 0; n < 7; ++n) w2[n] = Wg2[n * NH + j];

    // Register rings: records (ra,rb) and G2 rows (gg), depth 4.
    f32x4 ra[4], rb[4];
    f32x2 gg[4];
    ra[0] = xp[0]; rb[0] = xp[1];
    ra[1] = xp[2]; rb[1] = xp[3];
    ra[2] = xp[4]; rb[2] = xp[5];
    gg[0] = *(const f32x2*)(g2b + (size_t)(unsigned)__float_as_int(ra[0].x) + j8);
    gg[1] = *(const f32x2*)(g2b + (size_t)(unsigned)__float_as_int(ra[1].x) + j8);

    float A = 1.0f, Bv = 0.0f;
    #pragma unroll 4
    for (int t = 0; t < STEPS; ++t) {
        // prefetch: record t+3, G2 row t+2 (record t+2 loaded last iteration)
        ra[(t + 3) & 3] = xp[2 * (t + 3)];
        rb[(t + 3) & 3] = xp[2 * (t + 3) + 1];
        gg[(t + 2) & 3] = *(const f32x2*)(
            g2b + (size_t)(unsigned)__float_as_int(ra[(t + 2) & 3].x) + j8);

        const f32x4 xa = ra[t & 3];
        const f32x4 xb = rb[t & 3];
        f32x2 g = gg[t & 3];
        g = __builtin_elementwise_fma(w2[0], (f32x2){xa.y, xa.y}, g);
        g = __builtin_elementwise_fma(w2[1], (f32x2){xa.z, xa.z}, g);
        g = __builtin_elementwise_fma(w2[2], (f32x2){xa.w, xa.w}, g);
        g = __builtin_elementwise_fma(w2[3], (f32x2){xb.x, xb.x}, g);
        g = __builtin_elementwise_fma(w2[4], (f32x2){xb.y, xb.y}, g);
        g = __builtin_elementwise_fma(w2[5], (f32x2){xb.z, xb.z}, g);
        g = __builtin_elementwise_fma(w2[6], (f32x2){xb.w, xb.w}, g);

        const float ez = __builtin_amdgcn_exp2f(g.x);   // exp(-2 gz)
        const float ef = __builtin_amdgcn_exp2f(g.y);   // exp(-gf)
        const float az = 1.0f + ez, af = 1.0f + ef;
        const float r = __builtin_amdgcn_rcpf(az * af); // shared rcp
        const float f = r * az;                         // sigmoid(gf)
        const float z = fmaf(2.0f, r * af, -1.0f);      // tanh(gz)

        A *= f;
        Bv = fmaf(f, Bv - z, z);   // z + f*(Bv - z)
    }

    AB[(((size_t)c * NB + b) * 2 + 0) * NH + j] = A;
    AB[(((size_t)c * NB + b) * 2 + 1) * NH + j] = Bv;

    if (c == CHUNKS - 1) {
        const f32x4 la = xp[2 * (STEPS - 1)];
        const f32x4 lb = xp[2 * (STEPS - 1) + 1];
        const int eo = __float_as_int(la.x);
        float go = *(const float*)((const char*)Go + ((size_t)(unsigned)eo >> 1) + j * 4);
        const float xs[7] = {la.y, la.z, la.w, lb.x, lb.y, lb.z, lb.w};
        #pragma unroll
        for (int n = 0; n < 7; ++n) {
            go = fmaf(Wgo[n * NH + j], xs[n], go);
        }
        Olast[b * NH + j] = __builtin_amdgcn_rcpf(1.0f + __builtin_amdgcn_exp2f(go));
    }
}

__global__ __launch_bounds__(256) void combine_kernel(
    const float* __restrict__ AB,     // [CHUNKS][B][2][256]
    const float* __restrict__ Olast,  // [B][256]
    const float* __restrict__ Wout,   // [1][256]
    const float* __restrict__ bout,   // [1]
    float* __restrict__ out)          // [B][1]
{
    const int b = blockIdx.x;
    const int j = threadIdx.x;

    float h = 0.0f;
    #pragma unroll 8
    for (int c = 0; c < CHUNKS; ++c) {
        const float A  = AB[(((size_t)c * NB + b) * 2 + 0) * NH + j];
        const float Bv = AB[(((size_t)c * NB + b) * 2 + 1) * NH + j];
        h = fmaf(A, h, Bv);
    }
    float v = Olast[b * NH + j] * h * Wout[j];

    #pragma unroll
    for (int off = 32; off > 0; off >>= 1) v += __shfl_down(v, off);
    __shared__ float red[4];
    if ((j & 63) == 0) red[j >> 6] = v;
    __syncthreads();
    if (j == 0) out[b] = red[0] + red[1] + red[2] + red[3] + bout[0];
}

extern "C" void kernel_launch(void* const* d_in, const int* in_sizes, int n_in,
                              void* d_out, int out_size, void* d_ws, size_t ws_size,
                              hipStream_t stream) {
    const float* X    = (const float*)d_in[0];
    const float* emb  = (const float*)d_in[1];
    const float* Wn   = (const float*)d_in[2];
    const float* bn   = (const float*)d_in[3];
    const float* Wc   = (const float*)d_in[4];
    const float* bc   = (const float*)d_in[5];
    const float* Wout = (const float*)d_in[6];
    const float* bout = (const float*)d_in[7];
    float* out = (float*)d_out;

    f32x2* G2  = (f32x2*)d_ws;                        // 128*256 f32x2 (256 KB)
    float* Go  = (float*)(G2 + 128 * NH);             // 128*256 (128 KB)
    f32x2* Wg2 = (f32x2*)(Go + 128 * NH);             // 7*256 f32x2
    float* Wgo = (float*)(Wg2 + 7 * NH);              // 7*256
    float* AB  = Wgo + 7 * NH;                        // 32*64*2*256 (4 MB)
    float* Ol  = AB + (size_t)CHUNKS * NB * 2 * NH;   // 64*256
    float* Xp  = Ol + NB * NH;                        // (64*2048+4)*8 floats

    precompute_kernel<<<193, 256, 0, stream>>>(X, emb, Wn, bn, Wc, bc,
                                               G2, Go, Wg2, Wgo, Xp);
    dim3 grid(NB, CHUNKS);
    scan_kernel<<<grid, 256, 0, stream>>>(Xp, G2, Go, Wg2, Wgo, AB, Ol);
    combine_kernel<<<NB, 256, 0, stream>>>(AB, Ol, Wout, bout, out);
}

// Round 7
// 41.836 us; speedup vs baseline: 1.1199x; 1.1199x over previous
//
#include <hip/hip_runtime.h>

// QRNN fused kernel for MI355X.
// B=64, S=2048, VOCAB=128, HIDDEN=256, gates=768, emb=124, num=7.
//
//  - precompute_kernel (one grid, three roles):
//      blocks 0..255  : GEMM, one channel j per block, 256 thr = 128 e x 2 k-halves.
//                       emb^T staged in LDS (pad 129); Wc row k-stream is block-
//                       uniform -> s_load (scalar cache); LDS partial-sum reduce;
//                       b_num folded via bias. Writes exp2-domain tables
//                       G2[e][j]=(z',f') and Go[e][j]=o'. All 256 CUs busy (round-4
//                       version used 64 blocks -> 75% of the chip idle).
//      block  256     : Wg2/Wgo numeric weights (Wc[:,124:]@W_num, scaled).
//      blocks 257..384: packed records Xp[b*S+t] = {eo=e<<11 (int bits), x0..x6}.
//  - scan_kernel: EXACT round-4 structure (best measured: plain loop, s_load
//      records, no hand pipeline -- rounds 5/6 proved hand-scheduling regresses).
//      Affine recurrence h = f*h + (1-f)*z, chunked scan (32 chunks x 64 steps),
//      256 thr, 1 channel/thread, shared-rcp activation (3 trans/step).
//  - combine_kernel: fold 32 chunk affines, apply o (last step), dot W_out.

typedef float f32x2 __attribute__((ext_vector_type(2)));
typedef float f32x4 __attribute__((ext_vector_type(4)));

#define NB 64
#define NS 2048
#define NH 256
#define CHUNKS 32
#define STEPS (NS / CHUNKS)   // 64
#define LOG2E 1.4426950408889634f
#define PAD 129

__global__ __launch_bounds__(256) void precompute_kernel(
    const float* __restrict__ X,     // [B][S][8]
    const float* __restrict__ emb,   // [128][124]
    const float* __restrict__ Wn,    // [4][7]
    const float* __restrict__ bn,    // [4]
    const float* __restrict__ Wc,    // [768][128]
    const float* __restrict__ bc,    // [768]
    f32x2* __restrict__ G2,          // out [128e][256j]  (z', f') exp2-domain
    float* __restrict__ Go,          // out [128e][256j]  o'
    f32x2* __restrict__ Wg2,         // out [7][256]
    float* __restrict__ Wgo,         // out [7][256]
    float* __restrict__ Xp)          // out [B*S][8] packed records
{
    const int tid = threadIdx.x;
    const int blk = blockIdx.x;

    if (blk < 256) {
        __shared__ float M[124 * PAD];      // emb^T: M[k*PAD + e] = emb[e][k]
        __shared__ float P[3][2][128];      // k-half partial sums
        // ---- stage emb^T (coalesced dwordx4 reads, conflict-free writes)
        {
            const int e = tid >> 1, half = tid & 1;
            const f32x4* er4 = (const f32x4*)(emb + (size_t)e * 124);
            #pragma unroll
            for (int i = 0; i < 16; ++i) {
                const int idx = half * 16 + i;
                if (idx < 31) {
                    const f32x4 v = er4[idx];
                    const int k0 = idx * 4;
                    M[(k0 + 0) * PAD + e] = v.x;
                    M[(k0 + 1) * PAD + e] = v.y;
                    M[(k0 + 2) * PAD + e] = v.z;
                    M[(k0 + 3) * PAD + e] = v.w;
                }
            }
        }
        __syncthreads();

        const int e = tid & 127;
        const int h = tid >> 7;          // k-half
        const int j = blk;               // channel
        const int k0 = h * 62;

        // Wc row streams are block-uniform -> scalar loads
        const float* __restrict__ wzr = Wc + (size_t)j * 128;
        const float* __restrict__ wfr = Wc + (size_t)(j + 256) * 128;
        const float* __restrict__ wor = Wc + (size_t)(j + 512) * 128;

        float az = 0.f, af = 0.f, ao = 0.f;
        #pragma unroll 31
        for (int i = 0; i < 62; ++i) {
            const int k = k0 + i;
            const float mv = M[k * PAD + e];
            az = fmaf(wzr[k], mv, az);
            af = fmaf(wfr[k], mv, af);
            ao = fmaf(wor[k], mv, ao);
        }
        P[0][h][e] = az; P[1][h][e] = af; P[2][h][e] = ao;
        __syncthreads();

        if (h == 0) {
            float sz = P[0][0][e] + P[0][1][e] + bc[j];
            float sf = P[1][0][e] + P[1][1][e] + bc[j + 256];
            float so = P[2][0][e] + P[2][1][e] + bc[j + 512];
            #pragma unroll
            for (int m = 0; m < 4; ++m) {
                const float bm = bn[m];
                sz = fmaf(wzr[124 + m], bm, sz);
                sf = fmaf(wfr[124 + m], bm, sf);
                so = fmaf(wor[124 + m], bm, so);
            }
            G2[(size_t)e * NH + j] = (f32x2){sz * (-2.0f * LOG2E), sf * (-LOG2E)};
            Go[(size_t)e * NH + j] = so * (-LOG2E);
        }
    } else if (blk == 256) {
        const int j = tid;
        #pragma unroll
        for (int n = 0; n < 7; ++n) {
            float sz = 0.0f, sf = 0.0f, so = 0.0f;
            #pragma unroll
            for (int m = 0; m < 4; ++m) {
                const float wnm = Wn[m * 7 + n];
                sz = fmaf(Wc[(size_t)j * 128 + 124 + m], wnm, sz);
                sf = fmaf(Wc[(size_t)(j + 256) * 128 + 124 + m], wnm, sf);
                so = fmaf(Wc[(size_t)(j + 512) * 128 + 124 + m], wnm, so);
            }
            Wg2[n * NH + j] = (f32x2){sz * (-2.0f * LOG2E), sf * (-LOG2E)};
            Wgo[n * NH + j] = so * (-LOG2E);
        }
    } else {
        // packed record extraction: 128 blocks x 1024 records
        const f32x4* X4 = (const f32x4*)X;
        f32x4* Xp4 = (f32x4*)Xp;
        const int base = (blk - 257) * 1024 + tid;
        #pragma unroll
        for (int u = 0; u < 4; ++u) {
            const int idx = base + u * 256;
            f32x4 xa = X4[(size_t)idx * 2];
            const f32x4 xb = X4[(size_t)idx * 2 + 1];
            xa.x = __int_as_float(((int)xa.x) << 11);   // byte offset of G2 row (2KB)
            Xp4[(size_t)idx * 2]     = xa;
            Xp4[(size_t)idx * 2 + 1] = xb;
        }
    }
}

__global__ __launch_bounds__(256) void scan_kernel(
    const float* __restrict__ Xp,    // [B*S][8] packed records
    const f32x2* __restrict__ G2,    // [128][256]
    const float* __restrict__ Go,    // [128][256]
    const f32x2* __restrict__ Wg2,   // [7][256]
    const float* __restrict__ Wgo,   // [7][256]
    float* __restrict__ AB,          // [CHUNKS][B][2][256]
    float* __restrict__ Olast)       // [B][256]
{
    const int b = blockIdx.x;
    const int c = blockIdx.y;
    const int j = threadIdx.x;

    const float* __restrict__ xr = Xp + ((size_t)b * NS + (size_t)c * STEPS) * 8; // uniform
    const char* __restrict__ g2b = (const char*)G2;
    const int j8 = j * 8;

    f32x2 w2[7];
    #pragma unroll
    for (int n = 0; n < 7; ++n) w2[n] = Wg2[n * NH + j];

    float A = 1.0f, Bv = 0.0f;
    #pragma unroll 8
    for (int t = 0; t < STEPS; ++t) {
        const int eo = __float_as_int(xr[8 * t]);               // s_load, batched
        f32x2 g = *(const f32x2*)(g2b + (size_t)(unsigned)eo + j8);
        #pragma unroll
        for (int n = 0; n < 7; ++n) {
            const float xn = xr[8 * t + 1 + n];                 // s_load, batched
            g = __builtin_elementwise_fma(w2[n], (f32x2){xn, xn}, g);
        }
        const float ez = __builtin_amdgcn_exp2f(g.x);   // exp(-2 gz)
        const float ef = __builtin_amdgcn_exp2f(g.y);   // exp(-gf)
        const float az = 1.0f + ez, af = 1.0f + ef;
        const float r = __builtin_amdgcn_rcpf(az * af); // shared rcp
        const float f = r * az;                         // sigmoid(gf)
        const float z = fmaf(2.0f, r * af, -1.0f);      // tanh(gz)

        A *= f;
        Bv = fmaf(f, Bv - z, z);   // z + f*(Bv - z)
    }

    AB[(((size_t)c * NB + b) * 2 + 0) * NH + j] = A;
    AB[(((size_t)c * NB + b) * 2 + 1) * NH + j] = Bv;

    if (c == CHUNKS - 1) {
        const int t = STEPS - 1;
        const int eo = __float_as_int(xr[8 * t]);
        float go = *(const float*)((const char*)Go + ((size_t)(unsigned)eo >> 1) + j * 4);
        #pragma unroll
        for (int n = 0; n < 7; ++n) {
            go = fmaf(Wgo[n * NH + j], xr[8 * t + 1 + n], go);
        }
        Olast[b * NH + j] = __builtin_amdgcn_rcpf(1.0f + __builtin_amdgcn_exp2f(go));
    }
}

__global__ __launch_bounds__(256) void combine_kernel(
    const float* __restrict__ AB,     // [CHUNKS][B][2][256]
    const float* __restrict__ Olast,  // [B][256]
    const float* __restrict__ Wout,   // [1][256]
    const float* __restrict__ bout,   // [1]
    float* __restrict__ out)          // [B][1]
{
    const int b = blockIdx.x;
    const int j = threadIdx.x;

    float h = 0.0f;
    #pragma unroll 8
    for (int c = 0; c < CHUNKS; ++c) {
        const float A  = AB[(((size_t)c * NB + b) * 2 + 0) * NH + j];
        const float Bv = AB[(((size_t)c * NB + b) * 2 + 1) * NH + j];
        h = fmaf(A, h, Bv);
    }
    float v = Olast[b * NH + j] * h * Wout[j];

    #pragma unroll
    for (int off = 32; off > 0; off >>= 1) v += __shfl_down(v, off);
    __shared__ float red[4];
    if ((j & 63) == 0) red[j >> 6] = v;
    __syncthreads();
    if (j == 0) out[b] = red[0] + red[1] + red[2] + red[3] + bout[0];
}

extern "C" void kernel_launch(void* const* d_in, const int* in_sizes, int n_in,
                              void* d_out, int out_size, void* d_ws, size_t ws_size,
                              hipStream_t stream) {
    const float* X    = (const float*)d_in[0];
    const float* emb  = (const float*)d_in[1];
    const float* Wn   = (const float*)d_in[2];
    const float* bn   = (const float*)d_in[3];
    const float* Wc   = (const float*)d_in[4];
    const float* bc   = (const float*)d_in[5];
    const float* Wout = (const float*)d_in[6];
    const float* bout = (const float*)d_in[7];
    float* out = (float*)d_out;

    f32x2* G2  = (f32x2*)d_ws;                        // 128*256 f32x2 (256 KB)
    float* Go  = (float*)(G2 + 128 * NH);             // 128*256 (128 KB)
    f32x2* Wg2 = (f32x2*)(Go + 128 * NH);             // 7*256 f32x2
    float* Wgo = (float*)(Wg2 + 7 * NH);              // 7*256
    float* AB  = Wgo + 7 * NH;                        // 32*64*2*256 (4 MB)
    float* Ol  = AB + (size_t)CHUNKS * NB * 2 * NH;   // 64*256
    float* Xp  = Ol + NB * NH;                        // 64*2048*8 floats (4 MB)

    precompute_kernel<<<385, 256, 0, stream>>>(X, emb, Wn, bn, Wc, bc,
                                               G2, Go, Wg2, Wgo, Xp);
    dim3 grid(NB, CHUNKS);
    scan_kernel<<<grid, 256, 0, stream>>>(Xp, G2, Go, Wg2, Wgo, AB, Ol);
    combine_kernel<<<NB, 256, 0, stream>>>(AB, Ol, Wout, bout, out);
}

// Round 8
// 40.196 us; speedup vs baseline: 1.1656x; 1.0408x over previous
//
#include <hip/hip_runtime.h>

// QRNN fused kernel for MI355X.
// B=64, S=2048, VOCAB=128, HIDDEN=256, gates=768, emb=124, num=7.
//
//  - precompute_kernel (one grid, three roles):
//      blocks 0..255  : GEMM, one channel j per block, 256 thr = 128 e x 2 k-halves.
//                       emb^T staged in LDS (pad 129); Wc rows block-uniform -> s_load;
//                       b_num folded via bias. Writes exp2-domain tables
//                       G2[e][j]=(z',f'), Go[e][j]=o'.
//      block  256     : rank-4 numeric weights: Wg4[m][j] = scaled Wc[:,124+m] columns
//                       (z,f pair) and Wgo4[m][j] (o). W_num itself moves to extraction.
//      blocks 257..384: record extraction with the RANK-4 reduction: the numeric path
//                       factors through W_num (768x7 = (768x4)@(4x7)), so records carry
//                       y = W_num @ x (4 floats) instead of x (7): scan does 4 pk_fma
//                       per step instead of 7. Record = {eo=e<<11 bits, y0..y3, pad}.
//  - scan_kernel: affine recurrence h = f*h + (1-f)*z, chunked scan (32 x 64 steps),
//      256 thr, 1 channel/thread. FULL 64-step unroll: straight-line SSA lets the
//      scheduler hoist the uniform record s_loads (lgkmcnt) and keep many G2 gathers
//      (vmcnt) in flight -- the bounded unroll-8 loop serialized group-by-group
//      (s_load ~300cy -> gather ~300cy -> compute, repeat). Counters stay separated:
//      records never touch vmcnt. Shared-rcp activation: 2 exp2 + 1 rcp per step.
//  - combine_kernel: fold 32 chunk affines, apply o (last step), dot W_out.

typedef float f32x2 __attribute__((ext_vector_type(2)));
typedef float f32x4 __attribute__((ext_vector_type(4)));

#define NB 64
#define NS 2048
#define NH 256
#define CHUNKS 32
#define STEPS (NS / CHUNKS)   // 64
#define LOG2E 1.4426950408889634f
#define PAD 129

__global__ __launch_bounds__(256) void precompute_kernel(
    const float* __restrict__ X,     // [B][S][8]
    const float* __restrict__ emb,   // [128][124]
    const float* __restrict__ Wn,    // [4][7]
    const float* __restrict__ bn,    // [4]
    const float* __restrict__ Wc,    // [768][128]
    const float* __restrict__ bc,    // [768]
    f32x2* __restrict__ G2,          // out [128e][256j]  (z', f') exp2-domain
    float* __restrict__ Go,          // out [128e][256j]  o'
    f32x2* __restrict__ Wg4,         // out [4][256]
    float* __restrict__ Wgo4,        // out [4][256]
    float* __restrict__ Xp)          // out [B*S][8] packed rank-4 records
{
    const int tid = threadIdx.x;
    const int blk = blockIdx.x;

    if (blk < 256) {
        __shared__ float M[124 * PAD];      // emb^T: M[k*PAD + e] = emb[e][k]
        __shared__ float P[3][2][128];      // k-half partial sums
        {
            const int e = tid >> 1, half = tid & 1;
            const f32x4* er4 = (const f32x4*)(emb + (size_t)e * 124);
            #pragma unroll
            for (int i = 0; i < 16; ++i) {
                const int idx = half * 16 + i;
                if (idx < 31) {
                    const f32x4 v = er4[idx];
                    const int k0 = idx * 4;
                    M[(k0 + 0) * PAD + e] = v.x;
                    M[(k0 + 1) * PAD + e] = v.y;
                    M[(k0 + 2) * PAD + e] = v.z;
                    M[(k0 + 3) * PAD + e] = v.w;
                }
            }
        }
        __syncthreads();

        const int e = tid & 127;
        const int h = tid >> 7;          // k-half
        const int j = blk;               // channel
        const int k0 = h * 62;

        const float* __restrict__ wzr = Wc + (size_t)j * 128;
        const float* __restrict__ wfr = Wc + (size_t)(j + 256) * 128;
        const float* __restrict__ wor = Wc + (size_t)(j + 512) * 128;

        float az = 0.f, af = 0.f, ao = 0.f;
        #pragma unroll 31
        for (int i = 0; i < 62; ++i) {
            const int k = k0 + i;
            const float mv = M[k * PAD + e];
            az = fmaf(wzr[k], mv, az);
            af = fmaf(wfr[k], mv, af);
            ao = fmaf(wor[k], mv, ao);
        }
        P[0][h][e] = az; P[1][h][e] = af; P[2][h][e] = ao;
        __syncthreads();

        if (h == 0) {
            float sz = P[0][0][e] + P[0][1][e] + bc[j];
            float sf = P[1][0][e] + P[1][1][e] + bc[j + 256];
            float so = P[2][0][e] + P[2][1][e] + bc[j + 512];
            #pragma unroll
            for (int m = 0; m < 4; ++m) {
                const float bm = bn[m];
                sz = fmaf(wzr[124 + m], bm, sz);
                sf = fmaf(wfr[124 + m], bm, sf);
                so = fmaf(wor[124 + m], bm, so);
            }
            G2[(size_t)e * NH + j] = (f32x2){sz * (-2.0f * LOG2E), sf * (-LOG2E)};
            Go[(size_t)e * NH + j] = so * (-LOG2E);
        }
    } else if (blk == 256) {
        const int j = tid;
        #pragma unroll
        for (int m = 0; m < 4; ++m) {
            const float wz = Wc[(size_t)j * 128 + 124 + m];
            const float wf = Wc[(size_t)(j + 256) * 128 + 124 + m];
            const float wo = Wc[(size_t)(j + 512) * 128 + 124 + m];
            Wg4[m * NH + j]  = (f32x2){wz * (-2.0f * LOG2E), wf * (-LOG2E)};
            Wgo4[m * NH + j] = wo * (-LOG2E);
        }
    } else {
        // rank-4 record extraction: 128 blocks x 1024 records
        const f32x4* X4 = (const f32x4*)X;
        f32x4* Xp4 = (f32x4*)Xp;
        float wn[4][7];
        #pragma unroll
        for (int m = 0; m < 4; ++m)
            #pragma unroll
            for (int n = 0; n < 7; ++n) wn[m][n] = Wn[m * 7 + n];

        const int base = (blk - 257) * 1024 + tid;
        #pragma unroll
        for (int u = 0; u < 4; ++u) {
            const int idx = base + u * 256;
            const f32x4 xa = X4[(size_t)idx * 2];
            const f32x4 xb = X4[(size_t)idx * 2 + 1];
            const int eo = ((int)xa.x) << 11;   // byte offset of G2 row (2KB)
            const float xs[7] = {xa.y, xa.z, xa.w, xb.x, xb.y, xb.z, xb.w};
            float y[4];
            #pragma unroll
            for (int m = 0; m < 4; ++m) {
                float s = 0.0f;
                #pragma unroll
                for (int n = 0; n < 7; ++n) s = fmaf(wn[m][n], xs[n], s);
                y[m] = s;
            }
            Xp4[(size_t)idx * 2]     = (f32x4){__int_as_float(eo), y[0], y[1], y[2]};
            Xp4[(size_t)idx * 2 + 1] = (f32x4){y[3], 0.f, 0.f, 0.f};
        }
    }
}

__global__ __launch_bounds__(256) void scan_kernel(
    const float* __restrict__ Xp,    // [B*S][8] rank-4 records
    const f32x2* __restrict__ G2,    // [128][256]
    const float* __restrict__ Go,    // [128][256]
    const f32x2* __restrict__ Wg4,   // [4][256]
    const float* __restrict__ Wgo4,  // [4][256]
    float* __restrict__ AB,          // [CHUNKS][B][2][256]
    float* __restrict__ Olast)       // [B][256]
{
    const int b = blockIdx.x;
    const int c = blockIdx.y;
    const int j = threadIdx.x;

    const f32x4* __restrict__ xq =
        (const f32x4*)(Xp + ((size_t)b * NS + (size_t)c * STEPS) * 8);  // uniform
    const char* __restrict__ g2b = (const char*)G2;
    const int j8 = j * 8;

    const f32x2 w0 = Wg4[0 * NH + j];
    const f32x2 w1 = Wg4[1 * NH + j];
    const f32x2 w2 = Wg4[2 * NH + j];
    const f32x2 w3 = Wg4[3 * NH + j];

    float A = 1.0f, Bv = 0.0f;
    #pragma unroll
    for (int t = 0; t < STEPS; ++t) {
        const f32x4 ra = xq[2 * t];          // {eo bits, y0, y1, y2}  (s_load)
        const float y3 = xq[2 * t + 1].x;    // (s_load)
        f32x2 g = *(const f32x2*)(g2b + (size_t)(unsigned)__float_as_int(ra.x) + j8);
        g = __builtin_elementwise_fma(w0, (f32x2){ra.y, ra.y}, g);
        g = __builtin_elementwise_fma(w1, (f32x2){ra.z, ra.z}, g);
        g = __builtin_elementwise_fma(w2, (f32x2){ra.w, ra.w}, g);
        g = __builtin_elementwise_fma(w3, (f32x2){y3, y3}, g);

        const float ez = __builtin_amdgcn_exp2f(g.x);   // exp(-2 gz)
        const float ef = __builtin_amdgcn_exp2f(g.y);   // exp(-gf)
        const float az = 1.0f + ez, af = 1.0f + ef;
        const float r = __builtin_amdgcn_rcpf(az * af); // shared rcp
        const float f = r * az;                         // sigmoid(gf)
        const float z = fmaf(2.0f, r * af, -1.0f);      // tanh(gz)

        A *= f;
        Bv = fmaf(f, Bv - z, z);   // z + f*(Bv - z)
    }

    AB[(((size_t)c * NB + b) * 2 + 0) * NH + j] = A;
    AB[(((size_t)c * NB + b) * 2 + 1) * NH + j] = Bv;

    if (c == CHUNKS - 1) {
        const f32x4 la = xq[2 * (STEPS - 1)];
        const float ly3 = xq[2 * (STEPS - 1) + 1].x;
        const int eo = __float_as_int(la.x);
        float go = *(const float*)((const char*)Go + ((size_t)(unsigned)eo >> 1) + j * 4);
        go = fmaf(Wgo4[0 * NH + j], la.y, go);
        go = fmaf(Wgo4[1 * NH + j], la.z, go);
        go = fmaf(Wgo4[2 * NH + j], la.w, go);
        go = fmaf(Wgo4[3 * NH + j], ly3, go);
        Olast[b * NH + j] = __builtin_amdgcn_rcpf(1.0f + __builtin_amdgcn_exp2f(go));
    }
}

__global__ __launch_bounds__(256) void combine_kernel(
    const float* __restrict__ AB,     // [CHUNKS][B][2][256]
    const float* __restrict__ Olast,  // [B][256]
    const float* __restrict__ Wout,   // [1][256]
    const float* __restrict__ bout,   // [1]
    float* __restrict__ out)          // [B][1]
{
    const int b = blockIdx.x;
    const int j = threadIdx.x;

    float h = 0.0f;
    #pragma unroll 8
    for (int c = 0; c < CHUNKS; ++c) {
        const float A  = AB[(((size_t)c * NB + b) * 2 + 0) * NH + j];
        const float Bv = AB[(((size_t)c * NB + b) * 2 + 1) * NH + j];
        h = fmaf(A, h, Bv);
    }
    float v = Olast[b * NH + j] * h * Wout[j];

    #pragma unroll
    for (int off = 32; off > 0; off >>= 1) v += __shfl_down(v, off);
    __shared__ float red[4];
    if ((j & 63) == 0) red[j >> 6] = v;
    __syncthreads();
    if (j == 0) out[b] = red[0] + red[1] + red[2] + red[3] + bout[0];
}

extern "C" void kernel_launch(void* const* d_in, const int* in_sizes, int n_in,
                              void* d_out, int out_size, void* d_ws, size_t ws_size,
                              hipStream_t stream) {
    const float* X    = (const float*)d_in[0];
    const float* emb  = (const float*)d_in[1];
    const float* Wn   = (const float*)d_in[2];
    const float* bn   = (const float*)d_in[3];
    const float* Wc   = (const float*)d_in[4];
    const float* bc   = (const float*)d_in[5];
    const float* Wout = (const float*)d_in[6];
    const float* bout = (const float*)d_in[7];
    float* out = (float*)d_out;

    f32x2* G2   = (f32x2*)d_ws;                        // 128*256 f32x2 (256 KB)
    float* Go   = (float*)(G2 + 128 * NH);             // 128*256 (128 KB)
    f32x2* Wg4  = (f32x2*)(Go + 128 * NH);             // 4*256 f32x2
    float* Wgo4 = (float*)(Wg4 + 4 * NH);              // 4*256
    float* AB   = Wgo4 + 4 * NH;                       // 32*64*2*256 (4 MB)
    float* Ol   = AB + (size_t)CHUNKS * NB * 2 * NH;   // 64*256
    float* Xp   = Ol + NB * NH;                        // 64*2048*8 floats (4 MB)

    precompute_kernel<<<385, 256, 0, stream>>>(X, emb, Wn, bn, Wc, bc,
                                               G2, Go, Wg4, Wgo4, Xp);
    dim3 grid(NB, CHUNKS);
    scan_kernel<<<grid, 256, 0, stream>>>(Xp, G2, Go, Wg4, Wgo4, AB, Ol);
    combine_kernel<<<NB, 256, 0, stream>>>(AB, Ol, Wout, bout, out);
}